// Round 3
// baseline (1343.514 us; speedup 1.0000x reference)
//
#include <hip/hip_runtime.h>

typedef unsigned short u16;
typedef __attribute__((ext_vector_type(8))) short short8;   // bf16x8 MFMA operand (4 VGPRs)
typedef __attribute__((ext_vector_type(4))) float floatx4;  // MFMA accumulator

#define SCALE 0.17677669529663687f   // 32^-0.5 folded into q weights/bias

__device__ __forceinline__ u16 f2bf(float f){
  union { float f; unsigned u; } c; c.f = f;
  return (u16)((c.u + 0x7FFFu + ((c.u >> 16) & 1u)) >> 16);   // RNE
}

__device__ __forceinline__ void gl_lds16(const void* g, void* l){
  __builtin_amdgcn_global_load_lds((const __attribute__((address_space(1))) void*)g,
                                   (__attribute__((address_space(3))) void*)l, 16, 0, 0);
}

// ---------------- K0: weight prep (bf16 + scale fold) ----------------
__global__ __launch_bounds__(256) void k0_prep(const float* __restrict__ qkv_w,
                                               const float* __restrict__ qkv_b,
                                               const float* __restrict__ proj_w,
                                               u16* __restrict__ wqkv, u16* __restrict__ wproj,
                                               float* __restrict__ bq){
  const int i = blockIdx.x * 256 + threadIdx.x;
  if (i < 1152*384) wqkv[i] = f2bf(qkv_w[i] * ((i < 384*384) ? SCALE : 1.0f)); // rows n<384 are q
  if (i < 384*384)  wproj[i] = f2bf(proj_w[i]);
  if (i < 1152)     bq[i] = qkv_b[i] * ((i < 384) ? SCALE : 1.0f);
}

// ---------------- K1: window partition  x(B,C,H,W) fp32 -> win[M][384] bf16 ----------------
// block = (wx4, wy, b): 4 horizontal windows; LDS transpose [c 64][px 258-pad]
__global__ __launch_bounds__(256) void k1_part(const float* __restrict__ x, u16* __restrict__ win){
  __shared__ u16 lds[64][258];
  const int tid = threadIdx.x;
  const int wx4 = blockIdx.x, wy = blockIdx.y, b = blockIdx.z;
  const int hx0 = wx4 * 32;
  const long wbase = ((long)((b*28 + wy)*28) + wx4*4) * 64;
  for (int c0 = 0; c0 < 384; c0 += 64){
    #pragma unroll
    for (int p = 0; p < 16; p++){
      const int fidx = p*256 + tid;
      const int c = fidx >> 6, rem = fidx & 63;
      const int y = rem >> 3, x4 = rem & 7;
      const float4 v = *(const float4*)(x + (((long)(b*384 + c0 + c)*224 + wy*8 + y)*224 + hx0 + x4*4));
      const int px = y*32 + x4*4;
      *(unsigned*)&lds[c][px]     = (unsigned)f2bf(v.x) | ((unsigned)f2bf(v.y) << 16);
      *(unsigned*)&lds[c][px + 2] = (unsigned)f2bf(v.z) | ((unsigned)f2bf(v.w) << 16);
    }
    __syncthreads();
    #pragma unroll
    for (int p = 0; p < 8; p++){
      const int widx = p*256 + tid;
      const int px = widx >> 3, cp = widx & 7;
      const int y = px >> 5, hxo = px & 31;
      const long t = wbase + (hxo >> 3)*64 + y*8 + (hxo & 7);
      short8 vv;
      #pragma unroll
      for (int j = 0; j < 8; j++) vv[j] = (short)lds[cp*8 + j][px];
      *(short8*)(win + t*384 + c0 + cp*8) = vv;
    }
    __syncthreads();
  }
}

// ---------------- K2: QKV GEMM  [M x 384] @ [384 x 1152] (B^T = qkv_w), 128x128 tile ----------------
__global__ __launch_bounds__(256) void k2_gemm_qkv(const u16* __restrict__ A, const u16* __restrict__ Bw,
                                                   const float* __restrict__ bq,
                                                   u16* __restrict__ qo, u16* __restrict__ ko,
                                                   u16* __restrict__ vT){
  __shared__ u16 pool[17408];                 // 34816 B: 32KB staging / 34816B epilogue
  char* const ldsA = (char*)pool;
  char* const ldsB = (char*)pool + 16384;
  const int tid  = threadIdx.x;
  const int lane = tid & 63;
  const int wm = (tid >> 7) & 1, wn = (tid >> 6) & 1;
  const int nt = blockIdx.x;
  const int n0 = nt * 128;
  const long mbase = (long)blockIdx.y * 128;

  const floatx4 zero = {0.f, 0.f, 0.f, 0.f};
  floatx4 acc[4][4];
  #pragma unroll
  for (int r = 0; r < 4; r++)
    #pragma unroll
    for (int c = 0; c < 4; c++) acc[r][c] = zero;

  for (int kkb = 0; kkb < 6; kkb++){
    const int k0 = kkb * 64;
    #pragma unroll
    for (int cc = 0; cc < 4; cc++){
      const int idx = cc*256 + tid;
      const int m = idx >> 3, ch = idx & 7;
      const int ko2 = k0 + ((ch ^ (m & 7)) << 3);        // inverse-swizzled source (T2)
      gl_lds16(A  + (mbase + m)*384 + ko2, ldsA + (size_t)idx*16);
      gl_lds16(Bw + (long)(n0 + m)*384 + ko2, ldsB + (size_t)idx*16);
    }
    __syncthreads();
    short8 af[2][4], bf[2][4];
    #pragma unroll
    for (int ks = 0; ks < 2; ks++){
      const int kb = (ks*32 + ((lane >> 4) << 3)) * 2;
      #pragma unroll
      for (int r = 0; r < 4; r++){
        const int row = wm*64 + r*16 + (lane & 15);
        af[ks][r] = *(const short8*)(ldsA + row*128 + (kb ^ ((row & 7) << 4)));
      }
      #pragma unroll
      for (int c = 0; c < 4; c++){
        const int col = wn*64 + c*16 + (lane & 15);
        bf[ks][c] = *(const short8*)(ldsB + col*128 + (kb ^ ((col & 7) << 4)));
      }
    }
    #pragma unroll
    for (int ks = 0; ks < 2; ks++)
      #pragma unroll
      for (int r = 0; r < 4; r++)
        #pragma unroll
        for (int c = 0; c < 4; c++)
          acc[r][c] = __builtin_amdgcn_mfma_f32_16x16x32_bf16(af[ks][r], bf[ks][c], acc[r][c], 0, 0, 0);
    __syncthreads();
  }

  const int which = nt / 3;                    // 0=q 1=k 2=v
  if (which < 2){
    u16* const dst = (which == 0) ? qo : ko;
    u16 (* const ep)[136] = (u16(*)[136])pool;
    #pragma unroll
    for (int c = 0; c < 4; c++){
      const int col = wn*64 + c*16 + (lane & 15);
      const float badd = bq[n0 + col];
      #pragma unroll
      for (int r = 0; r < 4; r++){
        const int row0 = wm*64 + r*16 + ((lane >> 4) << 2);
        #pragma unroll
        for (int reg = 0; reg < 4; reg++)
          ep[row0 + reg][col] = f2bf(acc[r][c][reg] + badd);
      }
    }
    __syncthreads();
    const int cw = (nt - which*3) * 128;
    #pragma unroll
    for (int p = 0; p < 8; p++){
      const int widx = p*256 + tid;
      const int row = widx >> 4, cp = widx & 15;
      const short8 v = *(const short8*)&ep[row][cp*8];
      *(short8*)(dst + (mbase + row)*384 + cw + cp*8) = v;
    }
  } else {
    // v: write transposed  vT[win][h][d][tok]  (lane's 4 regs = 4 consecutive tokens)
    #pragma unroll
    for (int c = 0; c < 4; c++){
      const int col = wn*64 + c*16 + (lane & 15);
      const int cv = n0 - 768 + col;
      const int h = cv >> 5, d = cv & 31;
      const float badd = bq[n0 + col];
      #pragma unroll
      for (int r = 0; r < 4; r++){
        const long t0 = mbase + wm*64 + r*16 + ((lane >> 4) << 2);
        const long wwin = t0 >> 6; const int tok = (int)(t0 & 63);
        ushort4 u;
        u.x = f2bf(acc[r][c][0] + badd); u.y = f2bf(acc[r][c][1] + badd);
        u.z = f2bf(acc[r][c][2] + badd); u.w = f2bf(acc[r][c][3] + badd);
        *(ushort4*)(vT + ((wwin*12 + h)*32 + d)*64 + tok) = u;
      }
    }
  }
}

// ---------------- K3: per-window attention (block = window, 4 waves x 3 heads) ----------------
__global__ __launch_bounds__(256) void k3_attn(const u16* __restrict__ q, const u16* __restrict__ kk,
                                               const u16* __restrict__ vT, const float* __restrict__ btab,
                                               u16* __restrict__ aout){
  __shared__ u16 plds[4][64][72];              // per-wave P buffer, 16B-aligned rows
  const int tid = threadIdx.x, lane = tid & 63, wave = tid >> 6;
  const long win = blockIdx.x;
  u16 (* const pw)[72] = plds[wave];
  const int l15 = lane & 15, lg = lane >> 4;
  const int dk = lg << 3;
  const floatx4 zero = {0.f, 0.f, 0.f, 0.f};

  for (int hh = 0; hh < 3; hh++){
    const int h = wave*3 + hh;
    const u16* const qb = q  + (win*64)*384 + h*32;
    const u16* const kb = kk + (win*64)*384 + h*32;
    short8 aq[4], bk[4];
    #pragma unroll
    for (int r = 0; r < 4; r++) aq[r] = *(const short8*)(qb + (r*16 + l15)*384 + dk);
    #pragma unroll
    for (int c = 0; c < 4; c++) bk[c] = *(const short8*)(kb + (c*16 + l15)*384 + dk);

    floatx4 sacc[4][4];
    #pragma unroll
    for (int r = 0; r < 4; r++)
      #pragma unroll
      for (int c = 0; c < 4; c++) sacc[r][c] = zero;
    #pragma unroll
    for (int r = 0; r < 4; r++)
      #pragma unroll
      for (int c = 0; c < 4; c++)
        sacc[r][c] = __builtin_amdgcn_mfma_f32_16x16x32_bf16(aq[r], bk[c], sacc[r][c], 0, 0, 0);

    // bias + row softmax (row i lives in the 16 lanes sharing lg; 4 col-frags per lane)
    #pragma unroll
    for (int r = 0; r < 4; r++){
      float mx[4], sm[4];
      #pragma unroll
      for (int reg = 0; reg < 4; reg++){
        const int i = r*16 + (lg << 2) + reg;
        const int yi = i >> 3, xi = i & 7;
        float m = -1e30f;
        #pragma unroll
        for (int c = 0; c < 4; c++){
          const int j = c*16 + l15;
          const int rpi = (yi - (j >> 3) + 7)*15 + (xi - (j & 7) + 7);
          const float v = sacc[r][c][reg] + btab[rpi*12 + h];
          sacc[r][c][reg] = v;
          m = fmaxf(m, v);
        }
        mx[reg] = m;
      }
      #pragma unroll
      for (int s = 1; s < 16; s <<= 1)
        #pragma unroll
        for (int reg = 0; reg < 4; reg++) mx[reg] = fmaxf(mx[reg], __shfl_xor(mx[reg], s));
      #pragma unroll
      for (int reg = 0; reg < 4; reg++){
        float ssum = 0.f;
        #pragma unroll
        for (int c = 0; c < 4; c++){
          const float e = __expf(sacc[r][c][reg] - mx[reg]);
          sacc[r][c][reg] = e; ssum += e;
        }
        sm[reg] = ssum;
      }
      #pragma unroll
      for (int s = 1; s < 16; s <<= 1)
        #pragma unroll
        for (int reg = 0; reg < 4; reg++) sm[reg] += __shfl_xor(sm[reg], s);
      #pragma unroll
      for (int reg = 0; reg < 4; reg++){
        const float inv = 1.0f / sm[reg];
        const int i = r*16 + (lg << 2) + reg;
        #pragma unroll
        for (int c = 0; c < 4; c++)
          pw[i][c*16 + l15] = f2bf(sacc[r][c][reg] * inv);
      }
    }
    __syncthreads();

    // PV: out^T = v^T @ P^T   (A = vT rows contiguous, B = P rows from LDS)
    short8 av[2][2], bp[4][2];
    #pragma unroll
    for (int db = 0; db < 2; db++)
      #pragma unroll
      for (int ks = 0; ks < 2; ks++)
        av[db][ks] = *(const short8*)(vT + ((win*12 + h)*32 + db*16 + l15)*64 + ks*32 + dk);
    #pragma unroll
    for (int ib = 0; ib < 4; ib++)
      #pragma unroll
      for (int ks = 0; ks < 2; ks++)
        bp[ib][ks] = *(const short8*)&pw[ib*16 + l15][ks*32 + dk];

    floatx4 oacc[2][4];
    #pragma unroll
    for (int db = 0; db < 2; db++)
      #pragma unroll
      for (int ib = 0; ib < 4; ib++) oacc[db][ib] = zero;
    #pragma unroll
    for (int ks = 0; ks < 2; ks++)
      #pragma unroll
      for (int db = 0; db < 2; db++)
        #pragma unroll
        for (int ib = 0; ib < 4; ib++)
          oacc[db][ib] = __builtin_amdgcn_mfma_f32_16x16x32_bf16(av[db][ks], bp[ib][ks], oacc[db][ib], 0, 0, 0);

    #pragma unroll
    for (int db = 0; db < 2; db++)
      #pragma unroll
      for (int ib = 0; ib < 4; ib++){
        const int i = ib*16 + l15;
        const int d0 = db*16 + (lg << 2);
        ushort4 u;
        u.x = f2bf(oacc[db][ib][0]); u.y = f2bf(oacc[db][ib][1]);
        u.z = f2bf(oacc[db][ib][2]); u.w = f2bf(oacc[db][ib][3]);
        *(ushort4*)(aout + (win*64 + i)*384 + h*32 + d0) = u;
      }
    __syncthreads();
  }
}

// ---------------- K4: proj GEMM [M x 384] @ [384 x 384] + fused window reverse ----------------
__global__ __launch_bounds__(256) void k4_proj(const u16* __restrict__ A, const u16* __restrict__ Bw,
                                               const float* __restrict__ pb, float* __restrict__ out){
  __shared__ u16 pool[16384];                  // 32KB staging
  char* const ldsA = (char*)pool;
  char* const ldsB = (char*)pool + 16384;
  const int tid  = threadIdx.x;
  const int lane = tid & 63;
  const int wm = (tid >> 7) & 1, wn = (tid >> 6) & 1;
  const int n0 = blockIdx.x * 128;
  const long mbase = (long)blockIdx.y * 128;

  const floatx4 zero = {0.f, 0.f, 0.f, 0.f};
  floatx4 acc[4][4];
  #pragma unroll
  for (int r = 0; r < 4; r++)
    #pragma unroll
    for (int c = 0; c < 4; c++) acc[r][c] = zero;

  for (int kkb = 0; kkb < 6; kkb++){
    const int k0 = kkb * 64;
    #pragma unroll
    for (int cc = 0; cc < 4; cc++){
      const int idx = cc*256 + tid;
      const int m = idx >> 3, ch = idx & 7;
      const int ko2 = k0 + ((ch ^ (m & 7)) << 3);
      gl_lds16(A  + (mbase + m)*384 + ko2, ldsA + (size_t)idx*16);
      gl_lds16(Bw + (long)(n0 + m)*384 + ko2, ldsB + (size_t)idx*16);
    }
    __syncthreads();
    short8 af[2][4], bf[2][4];
    #pragma unroll
    for (int ks = 0; ks < 2; ks++){
      const int kb = (ks*32 + ((lane >> 4) << 3)) * 2;
      #pragma unroll
      for (int r = 0; r < 4; r++){
        const int row = wm*64 + r*16 + (lane & 15);
        af[ks][r] = *(const short8*)(ldsA + row*128 + (kb ^ ((row & 7) << 4)));
      }
      #pragma unroll
      for (int c = 0; c < 4; c++){
        const int col = wn*64 + c*16 + (lane & 15);
        bf[ks][c] = *(const short8*)(ldsB + col*128 + (kb ^ ((col & 7) << 4)));
      }
    }
    #pragma unroll
    for (int ks = 0; ks < 2; ks++)
      #pragma unroll
      for (int r = 0; r < 4; r++)
        #pragma unroll
        for (int c = 0; c < 4; c++)
          acc[r][c] = __builtin_amdgcn_mfma_f32_16x16x32_bf16(af[ks][r], bf[ks][c], acc[r][c], 0, 0, 0);
    __syncthreads();
  }

  // epilogue: +bias, window-reverse scatter (float4 = 4 consecutive hx)
  #pragma unroll
  for (int r = 0; r < 4; r++){
    const long t0 = mbase + wm*64 + r*16 + ((lane >> 4) << 2);
    const int wwin = (int)(t0 >> 6);
    const int b   = wwin / 784;
    const int wr  = wwin - b*784;
    const int wyy = wr / 28;
    const int wxx = wr - wyy*28;
    const int tk = (int)(t0 & 63);
    const int hy = wyy*8 + (tk >> 3);
    const int hx = wxx*8 + (tk & 7);
    #pragma unroll
    for (int c = 0; c < 4; c++){
      const int ch = n0 + wn*64 + c*16 + (lane & 15);
      const float badd = pb[ch];
      float4 v;
      v.x = acc[r][c][0] + badd; v.y = acc[r][c][1] + badd;
      v.z = acc[r][c][2] + badd; v.w = acc[r][c][3] + badd;
      *(float4*)(out + ((long)(b*384 + ch)*224 + hy)*224 + hx) = v;
    }
  }
}

// ---------------- launch ----------------
extern "C" void kernel_launch(void* const* d_in, const int* in_sizes, int n_in,
                              void* d_out, int out_size, void* d_ws, size_t ws_size,
                              hipStream_t stream){
  const float* x      = (const float*)d_in[0];
  const float* qkv_w  = (const float*)d_in[1];
  const float* qkv_b  = (const float*)d_in[2];
  const float* proj_w = (const float*)d_in[3];
  const float* proj_b = (const float*)d_in[4];
  const float* btab   = (const float*)d_in[5];

  char* ws = (char*)d_ws;
  // ws layout (~310 MB): win/aout @0 (154140672 B), vT @154140672 (154140672 B),
  // weights after. q and k live in d_out (308281344 B = exactly 2 x 154140672):
  // they are dead before K4 overwrites d_out with the final result.
  u16*  win   = (u16*)(ws);                   // K1 out / K2 in; reused as attn-out after K2
  u16*  vT    = (u16*)(ws + 154140672L);
  u16*  wqkv  = (u16*)(ws + 308281344L);
  u16*  wproj = (u16*)(ws + 309166080L);
  float* bq   = (float*)(ws + 309460992L);
  u16*  q     = (u16*)d_out;                  // scratch use of d_out
  u16*  kbuf  = (u16*)d_out + 77070336L;

  k0_prep<<<dim3(1728), dim3(256), 0, stream>>>(qkv_w, qkv_b, proj_w, wqkv, wproj, bq);
  k1_part<<<dim3(7, 28, 4), dim3(256), 0, stream>>>(x, win);
  k2_gemm_qkv<<<dim3(9, 1568), dim3(256), 0, stream>>>(win, wqkv, bq, q, kbuf, vT);
  k3_attn<<<dim3(3136), dim3(256), 0, stream>>>(q, kbuf, vT, btab, win);
  k4_proj<<<dim3(3, 1568), dim3(256), 0, stream>>>(win, wproj, proj_b, (float*)d_out);
}